// Round 6
// baseline (263.590 us; speedup 1.0000x reference)
//
#include <hip/hip_runtime.h>
#include <math.h>

#define DD 768
#define HH 16
#define DHH 48
#define NPOS 512
#define NIDX 2048
#define INV_SCALE 0.14433756729740643f   // 1/sqrt(768/16)
#define LN_EPS 1e-5f

typedef __bf16 bf16_t;
typedef __bf16 bf16x8 __attribute__((ext_vector_type(8)));
typedef float f32x4 __attribute__((ext_vector_type(4)));

__device__ __forceinline__ void g2lds16(const void* g, void* l) {
  __builtin_amdgcn_global_load_lds((const __attribute__((address_space(1))) void*)g,
                                   (__attribute__((address_space(3))) void*)l, 16, 0, 0);
}
// staging bank-swizzle: lane L of a 16-row issue block fetches 8-elem chunk
// (L&3)^((L>>3)&3); reader at (row, lq) finds chunk lq at position lq^((row>>1)&3).
__device__ __forceinline__ int stg_chunk(int lane) { return (lane & 3) ^ ((lane >> 3) & 3); }
__device__ __forceinline__ int rd_off(int row, int lq) {
  return row * 32 + ((lq ^ ((row >> 1) & 3)) << 3);
}

// ---------------------------------------------------------------------------
// prep: blocks 0-5 hist | rest: fp32->bf16 cvt (src=null -> zero fill)
// ---------------------------------------------------------------------------
struct CvtDesc { const float* src; bf16_t* dst; int n8; };
struct CvtBatch { CvtDesc d[13]; };

__global__ __launch_bounds__(256) void prep(const int* __restrict__ fpos,
                                            const int* __restrict__ tpos,
                                            int* __restrict__ CNT, CvtBatch cvb) {
  const int bid = blockIdx.x;
  const int tid = threadIdx.x;
  __shared__ int shist[NPOS];
  if (bid < 6) {
    const int b = bid >> 1, which = bid & 1;
    const int* src = (which ? tpos : fpos) + b * NIDX;
    for (int i = tid; i < NPOS; i += 256) shist[i] = 0;
    __syncthreads();
    for (int i = tid; i < NIDX; i += 256) atomicAdd(&shist[src[i] & (NPOS - 1)], 1);
    __syncthreads();
    for (int i = tid; i < NPOS; i += 256) CNT[bid * NPOS + i] = shist[i];
    return;
  }
  const CvtDesc de = cvb.d[(bid - 6) >> 6];
  for (int i = ((bid - 6) & 63) * 256 + tid; i < de.n8; i += 64 * 256) {
    bf16_t t[8];
    if (de.src) {
      const f32x4 a = *(const f32x4*)(de.src + (size_t)i * 8);
      const f32x4 b = *(const f32x4*)(de.src + (size_t)i * 8 + 4);
#pragma unroll
      for (int e = 0; e < 4; ++e) { t[e] = (bf16_t)a[e]; t[4 + e] = (bf16_t)b[e]; }
    } else {
#pragma unroll
      for (int e = 0; e < 8; ++e) t[e] = (bf16_t)0.f;
    }
    *(bf16x8*)(de.dst + (size_t)i * 8) = *(bf16x8*)t;
  }
}

// ---------------------------------------------------------------------------
// MFMA GEMM, 64x128 tile, dbuf single-barrier, swizzled staging.
// mode: 0 f32 out | 1 bf16 out | 2 bf16 transposed (C[c*512+r]) |
//       3 K-aug: c<768 -> bf16 C; 768<=c<784 -> f32 cb[r*16+c-768]
// ---------------------------------------------------------------------------
struct MDesc { const bf16_t* A; const bf16_t* B; const float* bias; void* C;
               float* cb; int mode; int ntiles; };
struct MBatch { MDesc d[18]; };

__global__ __launch_bounds__(256, 4) void gemm64(MBatch batch) {
  const MDesc de = batch.d[blockIdx.y];
  const int mt = blockIdx.x & 7, nt = blockIdx.x >> 3;   // 8 x up-to-7
  if (nt >= de.ntiles) return;
  const int m0 = mt * 64, n0 = nt * 128;

  __shared__ bf16_t SA[2][2048];   // [64][32] packed (swizzled chunks)
  __shared__ bf16_t SB[2][4096];   // [128][32]

  const int tid = threadIdx.x;
  const int w = tid >> 6, lane = tid & 63;
  const int wm = w >> 1, wn = w & 1;
  const int lm = lane & 15, lq = lane >> 4;
  const int sr = lane >> 2, sc = stg_chunk(lane);

  f32x4 acc[2][4] = {};

  auto stage = [&](int buf, int k0) {
#pragma unroll
    for (int c = 0; c < 3; ++c) {
      const int issue = w + c * 4;           // 0..11, wave-uniform
      if (issue < 4)
        g2lds16(de.A + (size_t)(m0 + issue * 16 + sr) * 768 + k0 + sc * 8,
                SA[buf] + issue * 512);
      else {
        const int e = issue - 4;
        g2lds16(de.B + (size_t)(n0 + e * 16 + sr) * 768 + k0 + sc * 8,
                SB[buf] + e * 512);
      }
    }
  };

  stage(0, 0);
  for (int k0i = 0; k0i < 24; ++k0i) {
    const int cur = k0i & 1;
    __syncthreads();
    if (k0i + 1 < 24) stage(cur ^ 1, (k0i + 1) * 32);
    bf16x8 af[2], bfr[4];
#pragma unroll
    for (int i = 0; i < 2; ++i)
      af[i] = *(const bf16x8*)(SA[cur] + rd_off(wm * 32 + i * 16 + lm, lq));
#pragma unroll
    for (int j = 0; j < 4; ++j)
      bfr[j] = *(const bf16x8*)(SB[cur] + rd_off(wn * 64 + j * 16 + lm, lq));
#pragma unroll
    for (int i = 0; i < 2; ++i)
#pragma unroll
      for (int j = 0; j < 4; ++j)
        acc[i][j] = __builtin_amdgcn_mfma_f32_16x16x32_bf16(af[i], bfr[j], acc[i][j], 0, 0, 0);
  }

#pragma unroll
  for (int i = 0; i < 2; ++i) {
    const int rbase = m0 + wm * 32 + i * 16 + lq * 4;
#pragma unroll
    for (int j = 0; j < 4; ++j) {
      const int c = n0 + wn * 64 + j * 16 + lm;
      const float bv = (de.bias && c < 768) ? de.bias[c] : 0.f;
#pragma unroll
      for (int r = 0; r < 4; ++r) {
        const float v = acc[i][j][r] + bv;
        if (de.mode == 0)      ((float*)de.C)[(size_t)(rbase + r) * 768 + c] = v;
        else if (de.mode == 1) ((bf16_t*)de.C)[(size_t)(rbase + r) * 768 + c] = (bf16_t)v;
        else if (de.mode == 2) ((bf16_t*)de.C)[(size_t)c * NPOS + rbase + r] = (bf16_t)v;
        else {
          if (c < 768)       ((bf16_t*)de.C)[(size_t)(rbase + r) * 768 + c] = (bf16_t)v;
          else if (c < 784)  de.cb[(size_t)(rbase + r) * 16 + (c - 768)] = v;
        }
      }
    }
  }
}

// ---------------------------------------------------------------------------
// Fused MFMA attention per (pd, h, 64-row f-tile) — full S strip in registers.
// Wave w owns j-strip [w*128, w*128+128); sa[32] f32x4 = S[64 x 128] per wave.
// One pass over k (Q read ONCE from HBM); per k0: Q tile shared, K strip
// wave-private, both g2lds-staged + bank-swizzled. Mix applied at A-fragment
// (pre-scaled by INV_SCALE). Then 4 sequential jt phases: owner wave exp's its
// strip into P (LDS), all waves run PV MFMA (ones-row gives denominator).
// LDS: 72 KB staging dbuf (reused for P/Vs) + 5.3 KB -> 2 blocks/CU.
// VGPR ~230 (sa 128 + pv 16 + frags) -> 8 waves/CU.
// ---------------------------------------------------------------------------
__global__ __launch_bounds__(256, 2) void attn_mfma(
    const bf16_t* __restrict__ Qg, const bf16_t* __restrict__ Kg,
    const bf16_t* __restrict__ Vt, const float* __restrict__ cbG,
    const int* __restrict__ CNT, const float* __restrict__ mix0,
    const float* __restrict__ mix1, bf16_t* __restrict__ CTX) {
  const int bid = blockIdx.x;             // 6*16*8 = 768
  const int ft = bid & 7, h = (bid >> 3) & 15, pd = bid >> 7;
  const int dir = pd & 1;
  const int f0 = ft * 64;

  // U: dbuf staging 2 x 18432 elems (Q 64x32 @0, K strips 4 x 128x32 @2048+w*4096)
  //    softmax phase reuse: P (64x136) @0, Vs (64x136) @8704
  __shared__ bf16_t U[36864];
  __shared__ float mixs[768];
  __shared__ float cbw[512];
  __shared__ float rowl[64];

  const int tid = threadIdx.x;
  const int w = tid >> 6, lane = tid & 63;
  const bf16_t* Qp = Qg + (size_t)pd * NPOS * DD;
  const bf16_t* Kp = Kg + (size_t)pd * NPOS * DD;
  const bf16_t* Vp = Vt + (size_t)pd * DD * NPOS + (size_t)h * DHH * NPOS;
  const float* mix = (dir ? mix1 : mix0) + h * DD;
  const int* cnt = CNT + ((pd & ~1) + (1 - dir)) * NPOS;  // to-side counts

  for (int i = tid; i < 768; i += 256) mixs[i] = mix[i] * INV_SCALE;
  for (int i = tid; i < 512; i += 256)
    cbw[i] = cbG[((size_t)pd * NPOS + i) * HH + h] * INV_SCALE + __logf((float)cnt[i]);

  const int lm = lane & 15, lq = lane >> 4;
  const int sr = lane >> 2, sc = stg_chunk(lane);

  // precomputed LDS read offsets (swizzle-resolved)
  int qoff[4], koff[8];
#pragma unroll
  for (int i = 0; i < 4; ++i) qoff[i] = rd_off(i * 16 + lm, lq);
#pragma unroll
  for (int j = 0; j < 8; ++j) koff[j] = 2048 + w * 4096 + rd_off(j * 16 + lm, lq);

  auto stage = [&](int buf, int k0) {
    bf16_t* base = U + buf * 18432;
    g2lds16(Qp + (size_t)(f0 + w * 16 + sr) * DD + k0 + sc * 8, base + w * 512);
#pragma unroll
    for (int e = 0; e < 8; ++e)
      g2lds16(Kp + (size_t)(w * 128 + e * 16 + sr) * DD + k0 + sc * 8,
              base + 2048 + w * 4096 + e * 512);
  };

  f32x4 sa[32];
#pragma unroll
  for (int t = 0; t < 32; ++t) sa[t] = (f32x4){0.f, 0.f, 0.f, 0.f};

  stage(0, 0);
  for (int k0i = 0; k0i < 24; ++k0i) {
    const int cur = k0i & 1;
    __syncthreads();                     // drains cur's g2lds (issued last iter)
    if (k0i + 1 < 24) stage(cur ^ 1, (k0i + 1) * 32);
    const bf16_t* base = U + cur * 18432;
    const int k0 = k0i * 32;
    const f32x4 mxa = *(const f32x4*)&mixs[k0 + lq * 8];
    const f32x4 mxb = *(const f32x4*)&mixs[k0 + lq * 8 + 4];
    bf16x8 af[4];
#pragma unroll
    for (int i = 0; i < 4; ++i) {
      const bf16x8 q = *(const bf16x8*)(base + qoff[i]);
      bf16_t t[8];
#pragma unroll
      for (int e = 0; e < 4; ++e) {
        t[e]     = (bf16_t)((float)q[e] * mxa[e]);
        t[4 + e] = (bf16_t)((float)q[4 + e] * mxb[e]);
      }
      af[i] = *(bf16x8*)t;
    }
#pragma unroll
    for (int j = 0; j < 8; ++j) {
      const bf16x8 bf = *(const bf16x8*)(base + koff[j]);
#pragma unroll
      for (int i = 0; i < 4; ++i)
        sa[i * 8 + j] = __builtin_amdgcn_mfma_f32_16x16x32_bf16(af[i], bf, sa[i * 8 + j], 0, 0, 0);
    }
  }

  // ---- softmax + PV, 4 sequential 128-j chunks ----
  f32x4 pv[4] = {};
  for (int jt = 0; jt < 4; ++jt) {
    const int j0 = jt * 128;
    __syncthreads();                     // k-loop reads / prev PV reads done

    // stage Vs (rows 0..47 = V^T chunk, row 48 = ones)
    for (int i = tid; i < 49 * 16; i += 256) {
      const int r = i >> 4, cc = i & 15;
      if (r < 48)
        *(bf16x8*)(U + 8704 + r * 136 + cc * 8) =
            *(const bf16x8*)(Vp + (size_t)r * NPOS + j0 + cc * 8);
      else {
        bf16_t ones[8];
#pragma unroll
        for (int e = 0; e < 8; ++e) ones[e] = (bf16_t)1.f;
        *(bf16x8*)(U + 8704 + 48 * 136 + cc * 8) = *(bf16x8*)ones;
      }
    }
    // owner wave: P chunk = exp(sa + cbw) -> LDS
    if (w == jt) {
#pragma unroll
      for (int jj = 0; jj < 8; ++jj) {
        const int col = jj * 16 + lm;
        const float cb = cbw[j0 + col];
#pragma unroll
        for (int i = 0; i < 4; ++i) {
          const int rb = i * 16 + lq * 4;
#pragma unroll
          for (int r = 0; r < 4; ++r)
            U[(rb + r) * 136 + col] = (bf16_t)__expf(sa[i * 8 + jj][r] + cb);
        }
      }
    }
    __syncthreads();

#pragma unroll
    for (int kk = 0; kk < 4; ++kk) {
      const bf16x8 pa = *(const bf16x8*)(U + (w * 16 + lm) * 136 + kk * 32 + lq * 8);
#pragma unroll
      for (int j = 0; j < 4; ++j) {
        const bf16x8 pb = *(const bf16x8*)(U + 8704 + (j * 16 + lm) * 136 + kk * 32 + lq * 8);
        pv[j] = __builtin_amdgcn_mfma_f32_16x16x32_bf16(pa, pb, pv[j], 0, 0, 0);
      }
    }
  }

  // epilogue: col 48 of D (j=3, lm==0) is the row denominator
  if (lm == 0) {
#pragma unroll
    for (int r = 0; r < 4; ++r) rowl[w * 16 + lq * 4 + r] = pv[3][r];
  }
  __syncthreads();
#pragma unroll
  for (int j = 0; j < 3; ++j) {
#pragma unroll
    for (int r = 0; r < 4; ++r) {
      const int fr = w * 16 + lq * 4 + r;
      CTX[((size_t)pd * NPOS + f0 + fr) * DD + h * DHH + j * 16 + lm] =
          (bf16_t)(pv[j][r] / rowl[fr]);
    }
  }
}

// ---------------------------------------------------------------------------
// Residual + LayerNorm + count-weighted mean -> out[b][dir*768 .. +768]
// ---------------------------------------------------------------------------
__global__ __launch_bounds__(256) void ln_mean_kernel(
    const float* __restrict__ hs, const float* __restrict__ XB,
    const int* __restrict__ CNT,
    const float* __restrict__ lng0, const float* __restrict__ lnb0,
    const float* __restrict__ lng1, const float* __restrict__ lnb1,
    float* __restrict__ out) {
  const int blk = blockIdx.x;          // (b*2+dir)*64 + chunk, 384 blocks
  const int chunk = blk & 63;
  const int pd = blk >> 6;
  const int b = pd >> 1, dir = pd & 1;
  const float* lng = dir ? lng1 : lng0;
  const float* lnb = dir ? lnb1 : lnb0;
  const int* cnt = CNT + pd * NPOS;    // from-side counts
  const float* hb = hs + (size_t)b * NPOS * DD;
  const float* xb = XB + (size_t)pd * NPOS * DD;

  __shared__ float wacc[4][DD];
  const int tid = threadIdx.x;
  const int wave = tid >> 6, lane = tid & 63;
  for (int d0 = tid; d0 < 4 * DD; d0 += 256) ((float*)wacc)[d0] = 0.f;
  __syncthreads();

  float lg[12], lb[12];
#pragma unroll
  for (int qd = 0; qd < 12; ++qd) {
    lg[qd] = lng[lane + qd * 64];
    lb[qd] = lnb[lane + qd * 64];
  }

  for (int rr = 0; rr < 2; ++rr) {
    const int p = chunk * 8 + wave * 2 + rr;
    float x[12];
    float s = 0.f, ss = 0.f;
#pragma unroll
    for (int qd = 0; qd < 12; ++qd) {
      const int d0 = lane + qd * 64;
      const float xv = hb[(size_t)p * DD + d0] + xb[(size_t)p * DD + d0];
      x[qd] = xv; s += xv; ss += xv * xv;
    }
#pragma unroll
    for (int o = 1; o < 64; o <<= 1) {
      s += __shfl_xor(s, o);
      ss += __shfl_xor(ss, o);
    }
    const float mu = s * (1.f / 768.f);
    const float var = ss * (1.f / 768.f) - mu * mu;
    const float rstd = rsqrtf(var + LN_EPS);
    const float wgt = (float)cnt[p];
    if (wgt != 0.f) {
#pragma unroll
      for (int qd = 0; qd < 12; ++qd) {
        const int d0 = lane + qd * 64;
        wacc[wave][d0] += wgt * (lg[qd] * (x[qd] - mu) * rstd + lb[qd]);
      }
    }
  }
  __syncthreads();
  for (int d0 = tid; d0 < DD; d0 += 256) {
    const float t = wacc[0][d0] + wacc[1][d0] + wacc[2][d0] + wacc[3][d0];
    atomicAdd(&out[b * 1536 + dir * 768 + d0], t * (1.f / 2048.f));
  }
}

// ---------------------------------------------------------------------------
extern "C" void kernel_launch(void* const* d_in, const int* in_sizes, int n_in,
                              void* d_out, int out_size, void* d_ws, size_t ws_size,
                              hipStream_t stream) {
  const float* hs  = (const float*)d_in[0];
  const int* fpos  = (const int*)d_in[1];
  const int* tpos  = (const int*)d_in[2];

  const float* Wq[2]; const float* Wk[2]; const float* Wcb[2]; const float* Wv[2];
  const float* Wd[2]; const float* mixp[2];
  const float* bv[2]; const float* bd[2]; const float* lng[2]; const float* lnb[2];
  for (int p = 0; p < 2; ++p) {
    const int base = 3 + p * 10;
    Wq[p]   = (const float*)d_in[base + 0];
    Wk[p]   = (const float*)d_in[base + 1];
    Wcb[p]  = (const float*)d_in[base + 2];
    Wv[p]   = (const float*)d_in[base + 3];
    Wd[p]   = (const float*)d_in[base + 4];
    mixp[p] = (const float*)d_in[base + 5];
    bv[p]   = (const float*)d_in[base + 6];
    bd[p]   = (const float*)d_in[base + 7];
    lng[p]  = (const float*)d_in[base + 8];
    lnb[p]  = (const float*)d_in[base + 9];
  }

  char* wsp = (char*)d_ws;
  size_t off = 0;
  auto alloc = [&](size_t bytes) { char* p = wsp + off; off = (off + bytes + 255) & ~(size_t)255; return p; };
  bf16_t* hsb  = (bf16_t*)alloc((size_t)3 * NPOS * DD * 2);
  bf16_t* Wb   = (bf16_t*)alloc((size_t)6 * DD * DD * 2);     // Wq0,Wv0,Wd0,Wq1,Wv1,Wd1
  bf16_t* WkCb = (bf16_t*)alloc((size_t)2 * 896 * DD * 2);    // [Wk;Wcb;pad] per pset
  bf16_t* Qbf  = (bf16_t*)alloc((size_t)6 * NPOS * DD * 2);
  bf16_t* Kbf  = (bf16_t*)alloc((size_t)6 * NPOS * DD * 2);
  bf16_t* VtG  = (bf16_t*)alloc((size_t)6 * DD * NPOS * 2);
  bf16_t* CTXb = (bf16_t*)alloc((size_t)6 * NPOS * DD * 2);
  float*  XB   = (float*) alloc((size_t)6 * NPOS * DD * 4);
  float*  cbG  = (float*) alloc((size_t)6 * NPOS * HH * 4);
  int*    CNTb = (int*)   alloc((size_t)6 * NPOS * 4);

  hipMemsetAsync(d_out, 0, (size_t)out_size * sizeof(float), stream);

  CvtBatch cvb{};
  cvb.d[0] = CvtDesc{hs, hsb, 3 * NPOS * DD / 8};
  for (int p = 0; p < 2; ++p) {
    cvb.d[1 + p * 3] = CvtDesc{Wq[p], Wb + (size_t)(p * 3 + 0) * DD * DD, DD * DD / 8};
    cvb.d[2 + p * 3] = CvtDesc{Wv[p], Wb + (size_t)(p * 3 + 1) * DD * DD, DD * DD / 8};
    cvb.d[3 + p * 3] = CvtDesc{Wd[p], Wb + (size_t)(p * 3 + 2) * DD * DD, DD * DD / 8};
    bf16_t* wk = WkCb + (size_t)p * 896 * DD;
    cvb.d[7 + p * 3] = CvtDesc{Wk[p], wk, DD * DD / 8};
    cvb.d[8 + p * 3] = CvtDesc{Wcb[p], wk + (size_t)768 * DD, 16 * DD / 8};
    cvb.d[9 + p * 3] = CvtDesc{nullptr, wk + (size_t)784 * DD, 112 * DD / 8};
  }
  prep<<<838, 256, 0, stream>>>(fpos, tpos, CNTb, cvb);

  // projection GEMMs: Q bf16, K' (K + content bias), V bf16-transposed
  MBatch gb{};
  int n = 0;
  for (int b = 0; b < 3; ++b)
    for (int p = 0; p < 2; ++p) {
      const int pd = b * 2 + p;
      const bf16_t* A = hsb + (size_t)b * NPOS * DD;
      const size_t o = (size_t)pd * NPOS * DD;
      gb.d[n++] = MDesc{A, Wb + (size_t)(p * 3 + 0) * DD * DD, nullptr, Qbf + o, nullptr, 1, 6};
      gb.d[n++] = MDesc{A, WkCb + (size_t)p * 896 * DD, nullptr, Kbf + o,
                        cbG + (size_t)pd * NPOS * HH, 3, 7};
      gb.d[n++] = MDesc{A, Wb + (size_t)(p * 3 + 1) * DD * DD, bv[p],
                        VtG + (size_t)pd * DD * NPOS, nullptr, 2, 6};
    }
  gemm64<<<dim3(56, 18), 256, 0, stream>>>(gb);

  attn_mfma<<<768, 256, 0, stream>>>(Qbf, Kbf, VtG, cbG, CNTb, mixp[0], mixp[1], CTXb);

  MBatch gd{};
  for (int b = 0; b < 3; ++b)
    for (int p = 0; p < 2; ++p) {
      const int pd = b * 2 + p;
      const size_t o = (size_t)pd * NPOS * DD;
      gd.d[pd] = MDesc{CTXb + o, Wb + (size_t)(p * 3 + 2) * DD * DD, bd[p],
                       XB + o, nullptr, 0, 6};
    }
  gemm64<<<dim3(56, 6), 256, 0, stream>>>(gd);

  ln_mean_kernel<<<384, 256, 0, stream>>>(hs, XB, CNTb, lng[0], lnb[0], lng[1], lnb[1],
                                          (float*)d_out);
}

// Round 7
// 245.781 us; speedup vs baseline: 1.0725x; 1.0725x over previous
//
#include <hip/hip_runtime.h>
#include <math.h>

#define DD 768
#define HH 16
#define DHH 48
#define NPOS 512
#define NIDX 2048
#define INV_SCALE 0.14433756729740643f   // 1/sqrt(768/16)
#define LN_EPS 1e-5f

typedef __bf16 bf16_t;
typedef __bf16 bf16x8 __attribute__((ext_vector_type(8)));
typedef float f32x4 __attribute__((ext_vector_type(4)));

__device__ __forceinline__ void g2lds16(const void* g, void* l) {
  __builtin_amdgcn_global_load_lds((const __attribute__((address_space(1))) void*)g,
                                   (__attribute__((address_space(3))) void*)l, 16, 0, 0);
}
// staging bank-swizzle: lane L of a 16-row issue block fetches 8-elem chunk
// (L&3)^((L>>3)&3); reader at (row, lq) finds chunk lq at position lq^((row>>1)&3).
__device__ __forceinline__ int stg_chunk(int lane) { return (lane & 3) ^ ((lane >> 3) & 3); }
__device__ __forceinline__ int rd_off(int row, int lq) {
  return row * 32 + ((lq ^ ((row >> 1) & 3)) << 3);
}

// ---------------------------------------------------------------------------
// prep: blocks 0-5 hist | rest: fp32->bf16 cvt (src=null -> zero fill)
// ---------------------------------------------------------------------------
struct CvtDesc { const float* src; bf16_t* dst; int n8; };
struct CvtBatch { CvtDesc d[13]; };

__global__ __launch_bounds__(256) void prep(const int* __restrict__ fpos,
                                            const int* __restrict__ tpos,
                                            int* __restrict__ CNT, CvtBatch cvb) {
  const int bid = blockIdx.x;
  const int tid = threadIdx.x;
  __shared__ int shist[NPOS];
  if (bid < 6) {
    const int b = bid >> 1, which = bid & 1;
    const int* src = (which ? tpos : fpos) + b * NIDX;
    for (int i = tid; i < NPOS; i += 256) shist[i] = 0;
    __syncthreads();
    for (int i = tid; i < NIDX; i += 256) atomicAdd(&shist[src[i] & (NPOS - 1)], 1);
    __syncthreads();
    for (int i = tid; i < NPOS; i += 256) CNT[bid * NPOS + i] = shist[i];
    return;
  }
  const CvtDesc de = cvb.d[(bid - 6) >> 6];
  for (int i = ((bid - 6) & 63) * 256 + tid; i < de.n8; i += 64 * 256) {
    bf16_t t[8];
    if (de.src) {
      const f32x4 a = *(const f32x4*)(de.src + (size_t)i * 8);
      const f32x4 b = *(const f32x4*)(de.src + (size_t)i * 8 + 4);
#pragma unroll
      for (int e = 0; e < 4; ++e) { t[e] = (bf16_t)a[e]; t[4 + e] = (bf16_t)b[e]; }
    } else {
#pragma unroll
      for (int e = 0; e < 8; ++e) t[e] = (bf16_t)0.f;
    }
    *(bf16x8*)(de.dst + (size_t)i * 8) = *(bf16x8*)t;
  }
}

// ---------------------------------------------------------------------------
// MFMA GEMM, 64x128 tile, dbuf single-barrier, swizzled staging.
// mode: 0 f32 out | 1 bf16 out | 2 bf16 transposed (C[c*512+r]) |
//       3 K-aug: c<768 -> bf16 C; 768<=c<784 -> f32 cb[r*16+c-768]
// ---------------------------------------------------------------------------
struct MDesc { const bf16_t* A; const bf16_t* B; const float* bias; void* C;
               float* cb; int mode; int ntiles; };
struct MBatch { MDesc d[18]; };

__global__ __launch_bounds__(256, 4) void gemm64(MBatch batch) {
  const MDesc de = batch.d[blockIdx.y];
  const int mt = blockIdx.x & 7, nt = blockIdx.x >> 3;   // 8 x up-to-7
  if (nt >= de.ntiles) return;
  const int m0 = mt * 64, n0 = nt * 128;

  __shared__ bf16_t SA[2][2048];   // [64][32] packed (swizzled chunks)
  __shared__ bf16_t SB[2][4096];   // [128][32]

  const int tid = threadIdx.x;
  const int w = tid >> 6, lane = tid & 63;
  const int wm = w >> 1, wn = w & 1;
  const int lm = lane & 15, lq = lane >> 4;
  const int sr = lane >> 2, sc = stg_chunk(lane);

  f32x4 acc[2][4] = {};

  auto stage = [&](int buf, int k0) {
#pragma unroll
    for (int c = 0; c < 3; ++c) {
      const int issue = w + c * 4;           // 0..11, wave-uniform
      if (issue < 4)
        g2lds16(de.A + (size_t)(m0 + issue * 16 + sr) * 768 + k0 + sc * 8,
                SA[buf] + issue * 512);
      else {
        const int e = issue - 4;
        g2lds16(de.B + (size_t)(n0 + e * 16 + sr) * 768 + k0 + sc * 8,
                SB[buf] + e * 512);
      }
    }
  };

  stage(0, 0);
  for (int k0i = 0; k0i < 24; ++k0i) {
    const int cur = k0i & 1;
    __syncthreads();
    if (k0i + 1 < 24) stage(cur ^ 1, (k0i + 1) * 32);
    bf16x8 af[2], bfr[4];
#pragma unroll
    for (int i = 0; i < 2; ++i)
      af[i] = *(const bf16x8*)(SA[cur] + rd_off(wm * 32 + i * 16 + lm, lq));
#pragma unroll
    for (int j = 0; j < 4; ++j)
      bfr[j] = *(const bf16x8*)(SB[cur] + rd_off(wn * 64 + j * 16 + lm, lq));
#pragma unroll
    for (int i = 0; i < 2; ++i)
#pragma unroll
      for (int j = 0; j < 4; ++j)
        acc[i][j] = __builtin_amdgcn_mfma_f32_16x16x32_bf16(af[i], bfr[j], acc[i][j], 0, 0, 0);
  }

#pragma unroll
  for (int i = 0; i < 2; ++i) {
    const int rbase = m0 + wm * 32 + i * 16 + lq * 4;
#pragma unroll
    for (int j = 0; j < 4; ++j) {
      const int c = n0 + wn * 64 + j * 16 + lm;
      const float bv = (de.bias && c < 768) ? de.bias[c] : 0.f;
#pragma unroll
      for (int r = 0; r < 4; ++r) {
        const float v = acc[i][j][r] + bv;
        if (de.mode == 0)      ((float*)de.C)[(size_t)(rbase + r) * 768 + c] = v;
        else if (de.mode == 1) ((bf16_t*)de.C)[(size_t)(rbase + r) * 768 + c] = (bf16_t)v;
        else if (de.mode == 2) ((bf16_t*)de.C)[(size_t)c * NPOS + rbase + r] = (bf16_t)v;
        else {
          if (c < 768)       ((bf16_t*)de.C)[(size_t)(rbase + r) * 768 + c] = (bf16_t)v;
          else if (c < 784)  de.cb[(size_t)(rbase + r) * 16 + (c - 768)] = v;
        }
      }
    }
  }
}

// ---------------------------------------------------------------------------
// Fused MFMA attention per (pd, h, 64-row f-tile), jt-loop structure.
// mixs pre-scaled & stored bf16: A-fragment repack is 8 native bf16 muls
// (no f32 cvt round trip). Bank-swizzled g2lds staging. Count folded via log;
// PV via MFMA with ones-row giving the softmax denominator.
// LDS ~39 KB -> all 768 blocks co-resident (3/CU avg). ~110 regs/wave.
// ---------------------------------------------------------------------------
__global__ __launch_bounds__(256, 4) void attn_mfma(
    const bf16_t* __restrict__ Qg, const bf16_t* __restrict__ Kg,
    const bf16_t* __restrict__ Vt, const float* __restrict__ cbG,
    const int* __restrict__ CNT, const float* __restrict__ mix0,
    const float* __restrict__ mix1, bf16_t* __restrict__ CTX) {
  const int bid = blockIdx.x;             // 6*16*8 = 768
  const int ft = bid & 7, h = (bid >> 3) & 15, pd = bid >> 7;
  const int dir = pd & 1;
  const int f0 = ft * 64;

  // U union, bf16 elems:
  //  staging dbuf: buf*6144 { Q 64x32 @0 (2048), K 128x32 @2048 (4096) }
  //  softmax:      P @0 (64x136 = 8704), Vs @8704 (64x136; rows0-47 V, 48 ones)
  __shared__ bf16_t U[17408];
  __shared__ bf16_t mixs[768];
  __shared__ float cbw[512];
  __shared__ float rowl[64];

  const int tid = threadIdx.x;
  const int w = tid >> 6, lane = tid & 63;
  const bf16_t* Qp = Qg + (size_t)pd * NPOS * DD;
  const bf16_t* Kp = Kg + (size_t)pd * NPOS * DD;
  const bf16_t* Vp = Vt + (size_t)pd * DD * NPOS + (size_t)h * DHH * NPOS;
  const float* mix = (dir ? mix1 : mix0) + h * DD;
  const int* cnt = CNT + ((pd & ~1) + (1 - dir)) * NPOS;  // to-side counts

  for (int i = tid; i < 768; i += 256) mixs[i] = (bf16_t)(mix[i] * INV_SCALE);
  for (int i = tid; i < 512; i += 256)
    cbw[i] = cbG[((size_t)pd * NPOS + i) * HH + h] * INV_SCALE + __logf((float)cnt[i]);

  const int wm = w >> 1, wn = w & 1;
  const int lm = lane & 15, lq = lane >> 4;
  const int sr = lane >> 2, sc = stg_chunk(lane);

  f32x4 pv[4] = {};

  for (int jt = 0; jt < 4; ++jt) {
    const int j0 = jt * 128;
    __syncthreads();                       // U free (init / prev jt's PV done)

    auto stage = [&](int buf, int k0) {
#pragma unroll
      for (int c = 0; c < 3; ++c) {
        const int issue = w + c * 4;       // wave-uniform 0..11
        if (issue < 4)
          g2lds16(Qp + (size_t)(f0 + issue * 16 + sr) * DD + k0 + sc * 8,
                  U + buf * 6144 + issue * 512);
        else {
          const int e = issue - 4;
          g2lds16(Kp + (size_t)(j0 + e * 16 + sr) * DD + k0 + sc * 8,
                  U + buf * 6144 + 2048 + e * 512);
        }
      }
    };

    stage(0, 0);
    f32x4 sa[2][4] = {};
    for (int k0i = 0; k0i < 24; ++k0i) {
      const int cur = k0i & 1;
      __syncthreads();                     // drains cur's g2lds
      if (k0i + 1 < 24) stage(cur ^ 1, (k0i + 1) * 32);
      const bf16x8 mx = *(const bf16x8*)&mixs[k0i * 32 + lq * 8];
      bf16x8 af[2], bfr[4];
#pragma unroll
      for (int i = 0; i < 2; ++i) {
        const bf16x8 q = *(const bf16x8*)(U + cur * 6144 + rd_off(wm * 32 + i * 16 + lm, lq));
        bf16_t t[8];
#pragma unroll
        for (int e = 0; e < 8; ++e) t[e] = (bf16_t)(q[e] * mx[e]);   // native bf16 mul
        af[i] = *(bf16x8*)t;
      }
#pragma unroll
      for (int j = 0; j < 4; ++j)
        bfr[j] = *(const bf16x8*)(U + cur * 6144 + 2048 + rd_off(wn * 64 + j * 16 + lm, lq));
#pragma unroll
      for (int i = 0; i < 2; ++i)
#pragma unroll
        for (int j = 0; j < 4; ++j)
          sa[i][j] = __builtin_amdgcn_mfma_f32_16x16x32_bf16(af[i], bfr[j], sa[i][j], 0, 0, 0);
    }
    __syncthreads();                       // staging reads done; U becomes P/Vs

    // P = exp(s + cbw)   (mix pre-scaled by INV_SCALE)
#pragma unroll
    for (int j = 0; j < 4; ++j) {
      const int col = wn * 64 + j * 16 + lm;
      const float cb = cbw[j0 + col];
#pragma unroll
      for (int i = 0; i < 2; ++i) {
        const int rbase = wm * 32 + i * 16 + lq * 4;
#pragma unroll
        for (int r = 0; r < 4; ++r)
          U[(rbase + r) * 136 + col] = (bf16_t)__expf(sa[i][j][r] + cb);
      }
    }
    // Vs rows 0..47 = V^T tile, row 48 = ones (denominator trick)
    for (int i = tid; i < 49 * 16; i += 256) {
      const int r = i >> 4, cc = i & 15;
      if (r < 48)
        *(bf16x8*)(U + 8704 + r * 136 + cc * 8) =
            *(const bf16x8*)(Vp + (size_t)r * NPOS + j0 + cc * 8);
      else {
        bf16_t ones[8];
#pragma unroll
        for (int e = 0; e < 8; ++e) ones[e] = (bf16_t)1.f;
        *(bf16x8*)(U + 8704 + 48 * 136 + cc * 8) = *(bf16x8*)ones;
      }
    }
    __syncthreads();

#pragma unroll
    for (int kk = 0; kk < 4; ++kk) {
      const bf16x8 pa = *(const bf16x8*)(U + (w * 16 + lm) * 136 + kk * 32 + lq * 8);
#pragma unroll
      for (int j = 0; j < 4; ++j) {
        const bf16x8 pb = *(const bf16x8*)(U + 8704 + (j * 16 + lm) * 136 + kk * 32 + lq * 8);
        pv[j] = __builtin_amdgcn_mfma_f32_16x16x32_bf16(pa, pb, pv[j], 0, 0, 0);
      }
    }
  }

  // epilogue: col 48 of D (j=3, lm==0) is the row denominator
  if (lm == 0) {
#pragma unroll
    for (int r = 0; r < 4; ++r) rowl[w * 16 + lq * 4 + r] = pv[3][r];
  }
  __syncthreads();
#pragma unroll
  for (int j = 0; j < 3; ++j) {
#pragma unroll
    for (int r = 0; r < 4; ++r) {
      const int fr = w * 16 + lq * 4 + r;
      CTX[((size_t)pd * NPOS + f0 + fr) * DD + h * DHH + j * 16 + lm] =
          (bf16_t)(pv[j][r] / rowl[fr]);
    }
  }
}

// ---------------------------------------------------------------------------
// Residual + LayerNorm + count-weighted mean -> out[b][dir*768 .. +768]
// ---------------------------------------------------------------------------
__global__ __launch_bounds__(256) void ln_mean_kernel(
    const float* __restrict__ hs, const float* __restrict__ XB,
    const int* __restrict__ CNT,
    const float* __restrict__ lng0, const float* __restrict__ lnb0,
    const float* __restrict__ lng1, const float* __restrict__ lnb1,
    float* __restrict__ out) {
  const int blk = blockIdx.x;          // (b*2+dir)*64 + chunk, 384 blocks
  const int chunk = blk & 63;
  const int pd = blk >> 6;
  const int b = pd >> 1, dir = pd & 1;
  const float* lng = dir ? lng1 : lng0;
  const float* lnb = dir ? lnb1 : lnb0;
  const int* cnt = CNT + pd * NPOS;    // from-side counts
  const float* hb = hs + (size_t)b * NPOS * DD;
  const float* xb = XB + (size_t)pd * NPOS * DD;

  __shared__ float wacc[4][DD];
  const int tid = threadIdx.x;
  const int wave = tid >> 6, lane = tid & 63;
  for (int d0 = tid; d0 < 4 * DD; d0 += 256) ((float*)wacc)[d0] = 0.f;
  __syncthreads();

  float lg[12], lb[12];
#pragma unroll
  for (int qd = 0; qd < 12; ++qd) {
    lg[qd] = lng[lane + qd * 64];
    lb[qd] = lnb[lane + qd * 64];
  }

  for (int rr = 0; rr < 2; ++rr) {
    const int p = chunk * 8 + wave * 2 + rr;
    float x[12];
    float s = 0.f, ss = 0.f;
#pragma unroll
    for (int qd = 0; qd < 12; ++qd) {
      const int d0 = lane + qd * 64;
      const float xv = hb[(size_t)p * DD + d0] + xb[(size_t)p * DD + d0];
      x[qd] = xv; s += xv; ss += xv * xv;
    }
#pragma unroll
    for (int o = 1; o < 64; o <<= 1) {
      s += __shfl_xor(s, o);
      ss += __shfl_xor(ss, o);
    }
    const float mu = s * (1.f / 768.f);
    const float var = ss * (1.f / 768.f) - mu * mu;
    const float rstd = rsqrtf(var + LN_EPS);
    const float wgt = (float)cnt[p];
    if (wgt != 0.f) {
#pragma unroll
      for (int qd = 0; qd < 12; ++qd) {
        const int d0 = lane + qd * 64;
        wacc[wave][d0] += wgt * (lg[qd] * (x[qd] - mu) * rstd + lb[qd]);
      }
    }
  }
  __syncthreads();
  for (int d0 = tid; d0 < DD; d0 += 256) {
    const float t = wacc[0][d0] + wacc[1][d0] + wacc[2][d0] + wacc[3][d0];
    atomicAdd(&out[b * 1536 + dir * 768 + d0], t * (1.f / 2048.f));
  }
}

// ---------------------------------------------------------------------------
extern "C" void kernel_launch(void* const* d_in, const int* in_sizes, int n_in,
                              void* d_out, int out_size, void* d_ws, size_t ws_size,
                              hipStream_t stream) {
  const float* hs  = (const float*)d_in[0];
  const int* fpos  = (const int*)d_in[1];
  const int* tpos  = (const int*)d_in[2];

  const float* Wq[2]; const float* Wk[2]; const float* Wcb[2]; const float* Wv[2];
  const float* Wd[2]; const float* mixp[2];
  const float* bv[2]; const float* bd[2]; const float* lng[2]; const float* lnb[2];
  for (int p = 0; p < 2; ++p) {
    const int base = 3 + p * 10;
    Wq[p]   = (const float*)d_in[base + 0];
    Wk[p]   = (const float*)d_in[base + 1];
    Wcb[p]  = (const float*)d_in[base + 2];
    Wv[p]   = (const float*)d_in[base + 3];
    Wd[p]   = (const float*)d_in[base + 4];
    mixp[p] = (const float*)d_in[base + 5];
    bv[p]   = (const float*)d_in[base + 6];
    bd[p]   = (const float*)d_in[base + 7];
    lng[p]  = (const float*)d_in[base + 8];
    lnb[p]  = (const float*)d_in[base + 9];
  }

  char* wsp = (char*)d_ws;
  size_t off = 0;
  auto alloc = [&](size_t bytes) { char* p = wsp + off; off = (off + bytes + 255) & ~(size_t)255; return p; };
  bf16_t* hsb  = (bf16_t*)alloc((size_t)3 * NPOS * DD * 2);
  bf16_t* Wb   = (bf16_t*)alloc((size_t)6 * DD * DD * 2);     // Wq0,Wv0,Wd0,Wq1,Wv1,Wd1
  bf16_t* WkCb = (bf16_t*)alloc((size_t)2 * 896 * DD * 2);    // [Wk;Wcb;pad] per pset
  bf16_t* Qbf  = (bf16_t*)alloc((size_t)6 * NPOS * DD * 2);
  bf16_t* Kbf  = (bf16_t*)alloc((size_t)6 * NPOS * DD * 2);
  bf16_t* VtG  = (bf16_t*)alloc((size_t)6 * DD * NPOS * 2);
  bf16_t* CTXb = (bf16_t*)alloc((size_t)6 * NPOS * DD * 2);
  float*  XB   = (float*) alloc((size_t)6 * NPOS * DD * 4);
  float*  cbG  = (float*) alloc((size_t)6 * NPOS * HH * 4);
  int*    CNTb = (int*)   alloc((size_t)6 * NPOS * 4);

  hipMemsetAsync(d_out, 0, (size_t)out_size * sizeof(float), stream);

  CvtBatch cvb{};
  cvb.d[0] = CvtDesc{hs, hsb, 3 * NPOS * DD / 8};
  for (int p = 0; p < 2; ++p) {
    cvb.d[1 + p * 3] = CvtDesc{Wq[p], Wb + (size_t)(p * 3 + 0) * DD * DD, DD * DD / 8};
    cvb.d[2 + p * 3] = CvtDesc{Wv[p], Wb + (size_t)(p * 3 + 1) * DD * DD, DD * DD / 8};
    cvb.d[3 + p * 3] = CvtDesc{Wd[p], Wb + (size_t)(p * 3 + 2) * DD * DD, DD * DD / 8};
    bf16_t* wk = WkCb + (size_t)p * 896 * DD;
    cvb.d[7 + p * 3] = CvtDesc{Wk[p], wk, DD * DD / 8};
    cvb.d[8 + p * 3] = CvtDesc{Wcb[p], wk + (size_t)768 * DD, 16 * DD / 8};
    cvb.d[9 + p * 3] = CvtDesc{nullptr, wk + (size_t)784 * DD, 112 * DD / 8};
  }
  prep<<<838, 256, 0, stream>>>(fpos, tpos, CNTb, cvb);

  // projection GEMMs: Q bf16, K' (K + content bias), V bf16-transposed
  MBatch gb{};
  int n = 0;
  for (int b = 0; b < 3; ++b)
    for (int p = 0; p < 2; ++p) {
      const int pd = b * 2 + p;
      const bf16_t* A = hsb + (size_t)b * NPOS * DD;
      const size_t o = (size_t)pd * NPOS * DD;
      gb.d[n++] = MDesc{A, Wb + (size_t)(p * 3 + 0) * DD * DD, nullptr, Qbf + o, nullptr, 1, 6};
      gb.d[n++] = MDesc{A, WkCb + (size_t)p * 896 * DD, nullptr, Kbf + o,
                        cbG + (size_t)pd * NPOS * HH, 3, 7};
      gb.d[n++] = MDesc{A, Wb + (size_t)(p * 3 + 1) * DD * DD, bv[p],
                        VtG + (size_t)pd * DD * NPOS, nullptr, 2, 6};
    }
  gemm64<<<dim3(56, 18), 256, 0, stream>>>(gb);

  attn_mfma<<<768, 256, 0, stream>>>(Qbf, Kbf, VtG, cbG, CNTb, mixp[0], mixp[1], CTXb);

  MBatch gd{};
  for (int b = 0; b < 3; ++b)
    for (int p = 0; p < 2; ++p) {
      const int pd = b * 2 + p;
      const size_t o = (size_t)pd * NPOS * DD;
      gd.d[pd] = MDesc{CTXb + o, Wb + (size_t)(p * 3 + 2) * DD * DD, bd[p],
                       XB + o, nullptr, 0, 6};
    }
  gemm64<<<dim3(56, 6), 256, 0, stream>>>(gd);

  ln_mean_kernel<<<384, 256, 0, stream>>>(hs, XB, CNTb, lng[0], lnb[0], lng[1], lnb[1],
                                          (float*)d_out);
}